// Round 1
// baseline (407.054 us; speedup 1.0000x reference)
//
#include <hip/hip_runtime.h>
#include <hip/hip_bf16.h>

// Problem dims
#define B_ 64
#define L_ 12
#define N_ 883
#define D_ 64
#define T_ 12
#define M_ 64
#define NTILES 14            // ceil(883/64)

typedef __bf16 bf16x8 __attribute__((ext_vector_type(8)));
typedef __bf16 bf16x4 __attribute__((ext_vector_type(4)));
typedef float  f32x4  __attribute__((ext_vector_type(4)));

// ---------------------------------------------------------------------------
// prep_all: (a) xs[b,n,d] = sum_l x[b,l,n,d], emitted pre-split as hi/lo bf16
//           (b) M fp32 -> Mh/Ml bf16 [t][m][d] and Mth bf16 [t][d][m]
// Blocks [0, 3532) do (a) (904192 float4s, exact); blocks [3532, 3724) do (b).
// ---------------------------------------------------------------------------
__global__ __launch_bounds__(256) void prep_all(const float* __restrict__ x,
                                                const float* __restrict__ M,
                                                __bf16* __restrict__ Mh,
                                                __bf16* __restrict__ Ml,
                                                __bf16* __restrict__ Mth,
                                                __bf16* __restrict__ xs_hi,
                                                __bf16* __restrict__ xs_lo) {
    const size_t XS_F4 = (size_t)B_ * N_ * 16;     // 904192 float4 outputs
    size_t idx = (size_t)blockIdx.x * 256 + threadIdx.x;
    if (idx < XS_F4) {
        size_t b   = idx / (N_ * 16);
        size_t rem = idx - b * (N_ * 16);          // n*16 + c4
        const f32x4* xp = (const f32x4*)x + b * (size_t)(L_ * N_ * 16) + rem;
        f32x4 s = f32x4{0.f, 0.f, 0.f, 0.f};
        #pragma unroll
        for (int l = 0; l < L_; ++l)
            s += xp[(size_t)l * (N_ * 16)];
        bf16x4 h4, l4;
        #pragma unroll
        for (int i = 0; i < 4; ++i) {
            __bf16 h = (__bf16)s[i];
            h4[i] = h;
            l4[i] = (__bf16)(s[i] - (float)h);
        }
        ((bf16x4*)xs_hi)[idx] = h4;
        ((bf16x4*)xs_lo)[idx] = l4;
    } else {
        size_t j = idx - XS_F4;
        if (j < (size_t)T_ * M_ * D_) {
            float v = M[j];
            __bf16 h = (__bf16)v;
            __bf16 l = (__bf16)(v - (float)h);
            Mh[j] = h;
            Ml[j] = l;
            int t = (int)(j >> 12);
            int m = (int)(j >> 6) & 63;
            int d = (int)j & 63;
            Mth[(t << 12) + (d << 6) + m] = h;
        }
    }
}

// ---------------------------------------------------------------------------
// Attention: one (b, n-tile, t) per block. No xs LDS stage, no __syncthreads:
// each lane loads its MFMA A-fragments (hi/lo bf16) straight from global
// (L2/L3-resident, 4x dwordx4). LDS holds only the per-wave P transpose
// buffer (9.2 KB) -> 8 blocks/CU, ~100% occupancy target.
// ---------------------------------------------------------------------------
__global__ __launch_bounds__(256, 8) void fused_attn(
        const __bf16* __restrict__ xs_hi,
        const __bf16* __restrict__ xs_lo,
        const __bf16* __restrict__ Mh,
        const __bf16* __restrict__ Ml,
        const __bf16* __restrict__ Mth,
        float* __restrict__ out) {
    __shared__ __bf16 pbf[4][16][72];   // per-wave private P staging

    const int tid  = threadIdx.x;
    const int lane = tid & 63;
    const int wave = tid >> 6;
    const int l15  = lane & 15;
    const int quad = lane >> 4;

    const int nt = blockIdx.x;          // fastest: same-t neighbors share M in L2
    const int t  = blockIdx.y;
    const int b  = blockIdx.z;
    const int n0 = nt * 64;

    // ---- A-fragments direct from global: row = n0 + wave*16 + l15 (clamped)
    const int arow  = n0 + wave * 16 + l15;
    const int arowc = arow < N_ ? arow : (N_ - 1);
    const __bf16* xh = xs_hi + ((size_t)b * N_ + arowc) * D_;
    const __bf16* xl = xs_lo + ((size_t)b * N_ + arowc) * D_;
    bf16x8 a_h[2], a_l[2];
    #pragma unroll
    for (int kc = 0; kc < 2; ++kc) {
        a_h[kc] = *(const bf16x8*)(xh + kc * 32 + quad * 8);
        a_l[kc] = *(const bf16x8*)(xl + kc * 32 + quad * 8);
    }

    const __bf16* mh  = Mh  + (t << 12);
    const __bf16* ml  = Ml  + (t << 12);
    const __bf16* mth = Mth + (t << 12);

    // ---- GEMM1: logits[n][m], hi/lo split (3 MFMAs per k-chunk)
    f32x4 c1[4];
    #pragma unroll
    for (int mt = 0; mt < 4; ++mt) c1[mt] = f32x4{0.f, 0.f, 0.f, 0.f};
    #pragma unroll
    for (int mt = 0; mt < 4; ++mt) {
        #pragma unroll
        for (int kc = 0; kc < 2; ++kc) {
            const __bf16* bp = mh + (size_t)(mt * 16 + l15) * 64 + kc * 32 + quad * 8;
            const __bf16* lp = ml + (size_t)(mt * 16 + l15) * 64 + kc * 32 + quad * 8;
            bf16x8 bh = *(const bf16x8*)bp;
            bf16x8 bl = *(const bf16x8*)lp;
            c1[mt] = __builtin_amdgcn_mfma_f32_16x16x32_bf16(a_h[kc], bh, c1[mt], 0, 0, 0);
            c1[mt] = __builtin_amdgcn_mfma_f32_16x16x32_bf16(a_l[kc], bh, c1[mt], 0, 0, 0);
            c1[mt] = __builtin_amdgcn_mfma_f32_16x16x32_bf16(a_h[kc], bl, c1[mt], 0, 0, 0);
        }
    }

    // ---- Softmax over m (64) per row; lane holds logits[quad*4+r][mt*16+l15].
    #pragma unroll
    for (int r = 0; r < 4; ++r) {
        float mx = fmaxf(fmaxf(c1[0][r], c1[1][r]), fmaxf(c1[2][r], c1[3][r]));
        #pragma unroll
        for (int off = 1; off < 16; off <<= 1)
            mx = fmaxf(mx, __shfl_xor(mx, off));
        float e[4];
        float s = 0.f;
        #pragma unroll
        for (int mt = 0; mt < 4; ++mt) {
            e[mt] = __expf(c1[mt][r] - mx);
            s += e[mt];
        }
        #pragma unroll
        for (int off = 1; off < 16; off <<= 1)
            s += __shfl_xor(s, off);
        float inv = 1.0f / s;
        #pragma unroll
        for (int mt = 0; mt < 4; ++mt)
            pbf[wave][quad * 4 + r][mt * 16 + l15] = (__bf16)(e[mt] * inv);
    }
    // pbf written/read by the SAME wave only -> in-order LDS, no barrier.

    // ---- GEMM2: value[n][d] = P @ M[t]
    bf16x8 pa[2];
    #pragma unroll
    for (int kc = 0; kc < 2; ++kc)
        pa[kc] = *(const bf16x8*)&pbf[wave][l15][kc * 32 + quad * 8];

    f32x4 c2[4];
    #pragma unroll
    for (int dt = 0; dt < 4; ++dt) c2[dt] = f32x4{0.f, 0.f, 0.f, 0.f};
    #pragma unroll
    for (int dt = 0; dt < 4; ++dt) {
        #pragma unroll
        for (int kc = 0; kc < 2; ++kc) {
            const __bf16* bp = mth + (size_t)(dt * 16 + l15) * 64 + kc * 32 + quad * 8;
            bf16x8 bv = *(const bf16x8*)bp;
            c2[dt] = __builtin_amdgcn_mfma_f32_16x16x32_bf16(pa[kc], bv, c2[dt], 0, 0, 0);
        }
    }

    // ---- Store: c2[dt][r] = value[n = wave*16+quad*4+r][d = dt*16+l15]
    float* op = out + ((size_t)(b * T_ + t) * N_ + n0) * D_;
    #pragma unroll
    for (int dt = 0; dt < 4; ++dt) {
        #pragma unroll
        for (int r = 0; r < 4; ++r) {
            int row = wave * 16 + quad * 4 + r;
            if (n0 + row < N_)
                op[(size_t)row * D_ + dt * 16 + l15] = c2[dt][r];
        }
    }
}

// ---------------------------------------------------------------------------
extern "C" void kernel_launch(void* const* d_in, const int* in_sizes, int n_in,
                              void* d_out, int out_size, void* d_ws, size_t ws_size,
                              hipStream_t stream) {
    const float* x = (const float*)d_in[0];
    const float* M = (const float*)d_in[1];
    float* out = (float*)d_out;

    __bf16* Mh    = (__bf16*)d_ws;                         // 12*64*64 bf16
    __bf16* Ml    = Mh + T_ * M_ * D_;
    __bf16* Mth   = Ml + T_ * M_ * D_;
    __bf16* xs_hi = Mth + T_ * M_ * D_;                    // B*N*64 bf16 = 7.24 MB
    __bf16* xs_lo = xs_hi + (size_t)B_ * N_ * D_;          // 7.24 MB

    const int xs_blocks   = (B_ * N_ * 16) / 256;          // 3532 exact
    const int prep_blocks = (T_ * M_ * D_ + 255) / 256;    // 192
    prep_all<<<xs_blocks + prep_blocks, 256, 0, stream>>>(x, M, Mh, Ml, Mth, xs_hi, xs_lo);

    fused_attn<<<dim3(NTILES, T_, B_), 256, 0, stream>>>(xs_hi, xs_lo, Mh, Ml, Mth, out);
}

// Round 2
// 329.391 us; speedup vs baseline: 1.2358x; 1.2358x over previous
//
#include <hip/hip_runtime.h>
#include <hip/hip_bf16.h>

// Problem dims
#define B_ 64
#define L_ 12
#define N_ 883
#define D_ 64
#define T_ 12
#define M_ 64
#define NTILES 14            // ceil(883/64)
#define NHALF 7              // n-tiles per block (2 halves)

typedef __bf16 bf16x8 __attribute__((ext_vector_type(8)));
typedef __bf16 bf16x4 __attribute__((ext_vector_type(4)));
typedef float  f32x4  __attribute__((ext_vector_type(4)));

// ---------------------------------------------------------------------------
// prep_all: (a) xs[b,n,d] = sum_l x[b,l,n,d], emitted pre-split as hi/lo bf16
//           (b) M fp32 -> Mh/Ml bf16 [t][m][d] and Mth bf16 [t][d][m]
// ---------------------------------------------------------------------------
__global__ __launch_bounds__(256) void prep_all(const float* __restrict__ x,
                                                const float* __restrict__ M,
                                                __bf16* __restrict__ Mh,
                                                __bf16* __restrict__ Ml,
                                                __bf16* __restrict__ Mth,
                                                __bf16* __restrict__ xs_hi,
                                                __bf16* __restrict__ xs_lo) {
    const size_t XS_F4 = (size_t)B_ * N_ * 16;     // 904192 float4 outputs
    size_t idx = (size_t)blockIdx.x * 256 + threadIdx.x;
    if (idx < XS_F4) {
        size_t b   = idx / (N_ * 16);
        size_t rem = idx - b * (N_ * 16);          // n*16 + c4
        const f32x4* xp = (const f32x4*)x + b * (size_t)(L_ * N_ * 16) + rem;
        f32x4 s = f32x4{0.f, 0.f, 0.f, 0.f};
        #pragma unroll
        for (int l = 0; l < L_; ++l)
            s += xp[(size_t)l * (N_ * 16)];
        bf16x4 h4, l4;
        #pragma unroll
        for (int i = 0; i < 4; ++i) {
            __bf16 h = (__bf16)s[i];
            h4[i] = h;
            l4[i] = (__bf16)(s[i] - (float)h);
        }
        ((bf16x4*)xs_hi)[idx] = h4;
        ((bf16x4*)xs_lo)[idx] = l4;
    } else {
        size_t j = idx - XS_F4;
        if (j < (size_t)T_ * M_ * D_) {
            float v = M[j];
            __bf16 h = (__bf16)v;
            __bf16 l = (__bf16)(v - (float)h);
            Mh[j] = h;
            Ml[j] = l;
            int t = (int)(j >> 12);
            int m = (int)(j >> 6) & 63;
            int d = (int)j & 63;
            Mth[(t << 12) + (d << 6) + m] = h;
        }
    }
}

// ---------------------------------------------------------------------------
// Attention: one block owns (b, t, n-half) and iterates 7 n-tiles.
// M fragments (GEMM1 hi/lo B-operands + GEMM2 B-operand) live in registers
// for the whole block: zero M traffic in the n-loop. Per n-tile a wave does
// 4 A-fragment loads (double-buffered, prefetched) + 32 MFMA + softmax +
// 16 stores. VGPR-heavy (~190) -> 2 waves/SIMD, which rounds 0/1 showed is
// sufficient (occupancy was not the limiter; VMEM contention was).
// ---------------------------------------------------------------------------
__global__ __launch_bounds__(256, 2) void fused_attn(
        const __bf16* __restrict__ xs_hi,
        const __bf16* __restrict__ xs_lo,
        const __bf16* __restrict__ Mh,
        const __bf16* __restrict__ Ml,
        const __bf16* __restrict__ Mth,
        float* __restrict__ out) {
    __shared__ __bf16 pbf[4][16][72];   // per-wave private P staging

    const int tid  = threadIdx.x;
    const int lane = tid & 63;
    const int wave = tid >> 6;
    const int l15  = lane & 15;
    const int quad = lane >> 4;

    const int nh = blockIdx.x;          // 0..1: n-tile half
    const int t  = blockIdx.y;
    const int b  = blockIdx.z;

    // ---- M fragments -> registers (once per block; reused for 7 n-tiles)
    const __bf16* mh  = Mh  + (t << 12);
    const __bf16* ml  = Ml  + (t << 12);
    const __bf16* mth = Mth + (t << 12);

    bf16x8 bmh[4][2], bml[4][2], bmv[4][2];
    #pragma unroll
    for (int mt = 0; mt < 4; ++mt) {
        #pragma unroll
        for (int kc = 0; kc < 2; ++kc) {
            const size_t off = (size_t)(mt * 16 + l15) * 64 + kc * 32 + quad * 8;
            bmh[mt][kc] = *(const bf16x8*)(mh + off);
            bml[mt][kc] = *(const bf16x8*)(ml + off);
            bmv[mt][kc] = *(const bf16x8*)(mth + off);
        }
    }

    const __bf16* xhb = xs_hi + (size_t)b * N_ * D_;
    const __bf16* xlb = xs_lo + (size_t)b * N_ * D_;
    float* outb = out + ((size_t)(b * T_ + t) * N_) * D_;

    // ---- double-buffered A fragments
    bf16x8 a_h[2][2], a_l[2][2];

    // prologue: load tile 0
    {
        const int n0   = nh * NHALF * 64;
        const int arow = n0 + wave * 16 + l15;
        const int arc  = arow < N_ ? arow : (N_ - 1);
        #pragma unroll
        for (int kc = 0; kc < 2; ++kc) {
            a_h[0][kc] = *(const bf16x8*)(xhb + (size_t)arc * D_ + kc * 32 + quad * 8);
            a_l[0][kc] = *(const bf16x8*)(xlb + (size_t)arc * D_ + kc * 32 + quad * 8);
        }
    }

    #pragma unroll
    for (int i = 0; i < NHALF; ++i) {
        const int cur = i & 1;
        const int n0  = (nh * NHALF + i) * 64;

        // prefetch next tile's A fragments
        if (i + 1 < NHALF) {
            const int arow = n0 + 64 + wave * 16 + l15;
            const int arc  = arow < N_ ? arow : (N_ - 1);
            #pragma unroll
            for (int kc = 0; kc < 2; ++kc) {
                a_h[cur ^ 1][kc] = *(const bf16x8*)(xhb + (size_t)arc * D_ + kc * 32 + quad * 8);
                a_l[cur ^ 1][kc] = *(const bf16x8*)(xlb + (size_t)arc * D_ + kc * 32 + quad * 8);
            }
        }

        // ---- GEMM1: logits[n][m], hi/lo split (3 MFMAs per k-chunk)
        f32x4 c1[4];
        #pragma unroll
        for (int mt = 0; mt < 4; ++mt) c1[mt] = f32x4{0.f, 0.f, 0.f, 0.f};
        #pragma unroll
        for (int mt = 0; mt < 4; ++mt) {
            #pragma unroll
            for (int kc = 0; kc < 2; ++kc) {
                c1[mt] = __builtin_amdgcn_mfma_f32_16x16x32_bf16(a_h[cur][kc], bmh[mt][kc], c1[mt], 0, 0, 0);
                c1[mt] = __builtin_amdgcn_mfma_f32_16x16x32_bf16(a_l[cur][kc], bmh[mt][kc], c1[mt], 0, 0, 0);
                c1[mt] = __builtin_amdgcn_mfma_f32_16x16x32_bf16(a_h[cur][kc], bml[mt][kc], c1[mt], 0, 0, 0);
            }
        }

        // ---- Softmax over m (64) per row; lane holds logits[quad*4+r][mt*16+l15].
        #pragma unroll
        for (int r = 0; r < 4; ++r) {
            float mx = fmaxf(fmaxf(c1[0][r], c1[1][r]), fmaxf(c1[2][r], c1[3][r]));
            #pragma unroll
            for (int off = 1; off < 16; off <<= 1)
                mx = fmaxf(mx, __shfl_xor(mx, off));
            float e[4];
            float s = 0.f;
            #pragma unroll
            for (int mt = 0; mt < 4; ++mt) {
                e[mt] = __expf(c1[mt][r] - mx);
                s += e[mt];
            }
            #pragma unroll
            for (int off = 1; off < 16; off <<= 1)
                s += __shfl_xor(s, off);
            float inv = 1.0f / s;
            #pragma unroll
            for (int mt = 0; mt < 4; ++mt)
                pbf[wave][quad * 4 + r][mt * 16 + l15] = (__bf16)(e[mt] * inv);
        }
        // pbf written/read by the SAME wave only -> in-order LDS, no barrier.

        // ---- GEMM2: value[n][d] = P @ M[t]
        bf16x8 pa[2];
        #pragma unroll
        for (int kc = 0; kc < 2; ++kc)
            pa[kc] = *(const bf16x8*)&pbf[wave][l15][kc * 32 + quad * 8];

        f32x4 c2[4];
        #pragma unroll
        for (int dt = 0; dt < 4; ++dt) c2[dt] = f32x4{0.f, 0.f, 0.f, 0.f};
        #pragma unroll
        for (int dt = 0; dt < 4; ++dt) {
            #pragma unroll
            for (int kc = 0; kc < 2; ++kc)
                c2[dt] = __builtin_amdgcn_mfma_f32_16x16x32_bf16(pa[kc], bmv[dt][kc], c2[dt], 0, 0, 0);
        }

        // ---- Store: c2[dt][r] = value[n = n0+wave*16+quad*4+r][d = dt*16+l15]
        float* op = outb + (size_t)n0 * D_;
        #pragma unroll
        for (int dt = 0; dt < 4; ++dt) {
            #pragma unroll
            for (int r = 0; r < 4; ++r) {
                int row = wave * 16 + quad * 4 + r;
                if (n0 + row < N_)
                    op[(size_t)row * D_ + dt * 16 + l15] = c2[dt][r];
            }
        }
    }
}

// ---------------------------------------------------------------------------
extern "C" void kernel_launch(void* const* d_in, const int* in_sizes, int n_in,
                              void* d_out, int out_size, void* d_ws, size_t ws_size,
                              hipStream_t stream) {
    const float* x = (const float*)d_in[0];
    const float* M = (const float*)d_in[1];
    float* out = (float*)d_out;

    __bf16* Mh    = (__bf16*)d_ws;                         // 12*64*64 bf16
    __bf16* Ml    = Mh + T_ * M_ * D_;
    __bf16* Mth   = Ml + T_ * M_ * D_;
    __bf16* xs_hi = Mth + T_ * M_ * D_;                    // B*N*64 bf16 = 7.24 MB
    __bf16* xs_lo = xs_hi + (size_t)B_ * N_ * D_;          // 7.24 MB

    const int xs_blocks   = (B_ * N_ * 16) / 256;          // 3532 exact
    const int prep_blocks = (T_ * M_ * D_ + 255) / 256;    // 192
    prep_all<<<xs_blocks + prep_blocks, 256, 0, stream>>>(x, M, Mh, Ml, Mth, xs_hi, xs_lo);

    fused_attn<<<dim3(2, T_, B_), 256, 0, stream>>>(xs_hi, xs_lo, Mh, Ml, Mth, out);
}